// Round 3
// baseline (2037.216 us; speedup 1.0000x reference)
//
#include <hip/hip_runtime.h>
#include <hip/hip_bf16.h>

// Problem: x[T=8,B=256,D=4096] fp32; W[D,D] fp32 (row o, col i); b[D] fp32.
// mm[t,b,o] = sum_i x[t,b,i]*W[o,i] + b[o]
// m_t = mm_t + m_{t-1}*(1-s_{t-1})*0.5 ; s_t = (m_t >= 1.0)
// Outputs m,s each [T,B,D], FLOAT32 (reference returns fp32), concatenated in d_out.
//
// Precision strategy: the hard threshold (m >= 1.0) means any GEMM-ordering
// difference vs the fp64 numpy reference that crosses 1.0 flips a spike and
// blows the absmax check (one flip -> error ~0.5*|m| >> 0.118 threshold).
// fp64 accumulation with exact fp32->fp64 products keeps our mm within
// ~1e-13 of the fp64 reference -> zero flips. Outputs rounded to fp32 (~3e-8).

#define T_DIM 8
#define B_DIM 256
#define D_DIM 4096
#define M_DIM (T_DIM * B_DIM)   // 2048 GEMM rows (t*B + b)

#define BM 64
#define BN 64
#define BK 16
#define NTHREADS 256

__global__ __launch_bounds__(NTHREADS) void gemm_f64_kernel(
    const float* __restrict__ X,    // [M_DIM][D_DIM]
    const float* __restrict__ W,    // [D_DIM][D_DIM], row-major [o][i]
    const float* __restrict__ bias, // [D_DIM]
    double* __restrict__ MM)        // [M_DIM][D_DIM] fp64 scratch (64 MiB)
{
    // LDS tiles stored transposed [k][m] as fp64 (convert once at staging).
    __shared__ double As[BK][BM + 2];
    __shared__ double Bs[BK][BN + 2];

    const int tid = threadIdx.x;
    const int bm = blockIdx.y * BM;
    const int bn = blockIdx.x * BN;

    // staging: each thread loads one float4 of A and one of W per k-step
    const int srow = tid >> 2;        // 0..63 (tile row)
    const int skq  = (tid & 3) << 2;  // 0,4,8,12 (k offset)

    // compute microtile: 16x16 thread grid
    // A rows: tm, tm+16, tm+32, tm+48 (interleaved -> conflict-free ds_read_b64)
    // B cols: tn..tn+3 (contiguous, broadcast across tm)
    const int tm = tid & 15;
    const int tn = (tid >> 4) << 2;

    double acc[4][4];
    #pragma unroll
    for (int i = 0; i < 4; ++i)
        #pragma unroll
        for (int j = 0; j < 4; ++j) acc[i][j] = 0.0;

    const float* xp = X + (size_t)(bm + srow) * D_DIM + skq;
    const float* wp = W + (size_t)(bn + srow) * D_DIM + skq;

    for (int k0 = 0; k0 < D_DIM; k0 += BK) {
        const float4 av = *reinterpret_cast<const float4*>(xp + k0);
        const float4 bv = *reinterpret_cast<const float4*>(wp + k0);
        __syncthreads();
        As[skq + 0][srow] = (double)av.x;
        As[skq + 1][srow] = (double)av.y;
        As[skq + 2][srow] = (double)av.z;
        As[skq + 3][srow] = (double)av.w;
        Bs[skq + 0][srow] = (double)bv.x;
        Bs[skq + 1][srow] = (double)bv.y;
        Bs[skq + 2][srow] = (double)bv.z;
        Bs[skq + 3][srow] = (double)bv.w;
        __syncthreads();

        #pragma unroll
        for (int kk = 0; kk < BK; ++kk) {
            const double a0 = As[kk][tm];
            const double a1 = As[kk][tm + 16];
            const double a2 = As[kk][tm + 32];
            const double a3 = As[kk][tm + 48];
            const double b0 = Bs[kk][tn + 0];
            const double b1 = Bs[kk][tn + 1];
            const double b2 = Bs[kk][tn + 2];
            const double b3 = Bs[kk][tn + 3];
            acc[0][0] = fma(a0, b0, acc[0][0]);
            acc[0][1] = fma(a0, b1, acc[0][1]);
            acc[0][2] = fma(a0, b2, acc[0][2]);
            acc[0][3] = fma(a0, b3, acc[0][3]);
            acc[1][0] = fma(a1, b0, acc[1][0]);
            acc[1][1] = fma(a1, b1, acc[1][1]);
            acc[1][2] = fma(a1, b2, acc[1][2]);
            acc[1][3] = fma(a1, b3, acc[1][3]);
            acc[2][0] = fma(a2, b0, acc[2][0]);
            acc[2][1] = fma(a2, b1, acc[2][1]);
            acc[2][2] = fma(a2, b2, acc[2][2]);
            acc[2][3] = fma(a2, b3, acc[2][3]);
            acc[3][0] = fma(a3, b0, acc[3][0]);
            acc[3][1] = fma(a3, b1, acc[3][1]);
            acc[3][2] = fma(a3, b2, acc[3][2]);
            acc[3][3] = fma(a3, b3, acc[3][3]);
        }
    }

    #pragma unroll
    for (int i = 0; i < 4; ++i) {
        const int row = bm + tm + 16 * i;
        double* mrow = MM + (size_t)row * D_DIM + bn + tn;
        #pragma unroll
        for (int j = 0; j < 4; ++j)
            mrow[j] = acc[i][j] + (double)bias[bn + tn + j];
    }
}

__global__ __launch_bounds__(256) void recur_kernel(
    const double* __restrict__ MM,
    float* __restrict__ out)   // fp32 outputs: m then s, each [T,B,D]
{
    const size_t stride = (size_t)B_DIM * D_DIM;  // 1,048,576
    const size_t idx = (size_t)blockIdx.x * 256 + threadIdx.x;  // b*D + o

    float* out_m = out;
    float* out_s = out + (size_t)T_DIM * stride;

    double m_prev = 0.0;
    double s_prev = 0.0;
    #pragma unroll
    for (int t = 0; t < T_DIM; ++t) {
        const double mm = MM[(size_t)t * stride + idx];
        // exactly one fp64 rounding (the add): (1-s) and *0.5 are exact
        const double m = mm + m_prev * (1.0 - s_prev) * 0.5;
        const double s = (m >= 1.0) ? 1.0 : 0.0;
        out_m[(size_t)t * stride + idx] = (float)m;
        out_s[(size_t)t * stride + idx] = (float)s;
        m_prev = m;
        s_prev = s;
    }
}

extern "C" void kernel_launch(void* const* d_in, const int* in_sizes, int n_in,
                              void* d_out, int out_size, void* d_ws, size_t ws_size,
                              hipStream_t stream) {
    // Identify inputs by element count (defensive; dict order is x, W, b).
    const float* x = (const float*)d_in[0];
    const float* W = (const float*)d_in[1];
    const float* b = (const float*)d_in[2];
    for (int i = 0; i < n_in; ++i) {
        if (in_sizes[i] == D_DIM) b = (const float*)d_in[i];
        else if (in_sizes[i] == D_DIM * D_DIM) W = (const float*)d_in[i];
        else if (in_sizes[i] == M_DIM * D_DIM) x = (const float*)d_in[i];
    }

    double* MM = (double*)d_ws;  // needs M_DIM*D_DIM*8 = 64 MiB

    dim3 grid_gemm(D_DIM / BN, M_DIM / BM);  // (64, 32)
    gemm_f64_kernel<<<grid_gemm, NTHREADS, 0, stream>>>(x, W, b, MM);

    const int n_bd = B_DIM * D_DIM;  // 1,048,576
    recur_kernel<<<n_bd / 256, 256, 0, stream>>>(MM, (float*)d_out);
}

// Round 5
// 1480.401 us; speedup vs baseline: 1.3761x; 1.3761x over previous
//
#include <hip/hip_runtime.h>
#include <hip/hip_bf16.h>

// Problem: x[T=8,B=256,D=4096] fp32; W[D,D] fp32 (row o, col i); b[D] fp32.
// mm[t,b,o] = sum_i x[t,b,i]*W[o,i] + b[o]
// m_t = mm_t + m_{t-1}*(1-s_{t-1})*0.5 ; s_t = (m_t >= 1.0)
// Outputs m,s each [T,B,D], fp32, concatenated in d_out.
//
// Precision: hard threshold (m >= 1.0) -> fp64 accumulation mandatory
// (Round 3 verified: passes with absmax = bf16-compare rounding floor).
//
// Round 5: stay on the PROVEN fp64 vector pipe (Round 4's f64-MFMA layout
// gamble failed; f64 matrix rate == vector rate anyway, 78.6 TF).
// Round 3 was LDS-byte-bound (4x4 microtile = 0.5 FLOP/LDS-byte -> 34.5 TF
// roof; measured 30.5). Fix: 128x128 tile, 8x8 microtile, float-in-LDS
// (2 FLOP/B), convert at fragment read, double-buffered, 1 barrier/K-tile.

#define T_DIM 8
#define B_DIM 256
#define D_DIM 4096
#define M_DIM (T_DIM * B_DIM)   // 2048 GEMM rows

#define BM 128
#define BN 128
#define BK 16
#define NT (D_DIM / BK)         // 256 K-tiles
#define LDSF (BM + 2)           // 130-float row stride (staging writes 2-way)

__global__ __launch_bounds__(256, 2) void gemm_f64v_kernel(
    const float* __restrict__ X,    // [M_DIM][D_DIM]
    const float* __restrict__ W,    // [D_DIM][D_DIM] row-major [o][i]
    const float* __restrict__ bias, // [D_DIM]
    double* __restrict__ MM)        // [M_DIM][D_DIM] fp64 scratch (64 MiB)
{
    // float tiles, [k][m] layout, double-buffered
    __shared__ float As[2][BK][LDSF];
    __shared__ float Bs[2][BK][LDSF];

    const int tid = threadIdx.x;
    const int bm = blockIdx.y * BM;
    const int bn = blockIdx.x * BN;

    // staging: thread -> (row sr, k-half sk); two float4 (8 k's) per array
    const int sr = tid >> 1;          // 0..127
    const int sk = (tid & 1) * 8;     // 0 or 8

    // compute: 16x16 thread grid; rows 2*tm+{0,1}+32i (i<4), cols tn..tn+7
    const int tm = tid & 15;
    const int tn = (tid >> 4) * 8;

    double acc[8][8];
    #pragma unroll
    for (int r = 0; r < 8; ++r)
        #pragma unroll
        for (int c = 0; c < 8; ++c) acc[r][c] = 0.0;

    const float* xp = X + (size_t)(bm + sr) * D_DIM + sk;
    const float* wp = W + (size_t)(bn + sr) * D_DIM + sk;

    // prologue: stage tile 0 into buffer 0
    {
        const float4 va0 = *reinterpret_cast<const float4*>(xp);
        const float4 va1 = *reinterpret_cast<const float4*>(xp + 4);
        const float4 vb0 = *reinterpret_cast<const float4*>(wp);
        const float4 vb1 = *reinterpret_cast<const float4*>(wp + 4);
        As[0][sk + 0][sr] = va0.x; As[0][sk + 1][sr] = va0.y;
        As[0][sk + 2][sr] = va0.z; As[0][sk + 3][sr] = va0.w;
        As[0][sk + 4][sr] = va1.x; As[0][sk + 5][sr] = va1.y;
        As[0][sk + 6][sr] = va1.z; As[0][sk + 7][sr] = va1.w;
        Bs[0][sk + 0][sr] = vb0.x; Bs[0][sk + 1][sr] = vb0.y;
        Bs[0][sk + 2][sr] = vb0.z; Bs[0][sk + 3][sr] = vb0.w;
        Bs[0][sk + 4][sr] = vb1.x; Bs[0][sk + 5][sr] = vb1.y;
        Bs[0][sk + 6][sr] = vb1.z; Bs[0][sk + 7][sr] = vb1.w;
    }
    __syncthreads();

    for (int t = 0; t < NT; ++t) {
        const int cur = t & 1;

        // issue next-tile global loads early (latency hides under compute)
        float4 na0, na1, nb0, nb1;
        if (t < NT - 1) {
            const int k0 = (t + 1) * BK;
            na0 = *reinterpret_cast<const float4*>(xp + k0);
            na1 = *reinterpret_cast<const float4*>(xp + k0 + 4);
            nb0 = *reinterpret_cast<const float4*>(wp + k0);
            nb1 = *reinterpret_cast<const float4*>(wp + k0 + 4);
        }

        // compute current tile
        #pragma unroll 4
        for (int kk = 0; kk < BK; ++kk) {
            double a[8], bb[8];
            #pragma unroll
            for (int i = 0; i < 4; ++i) {
                a[2 * i]     = (double)As[cur][kk][2 * tm + 32 * i];
                a[2 * i + 1] = (double)As[cur][kk][2 * tm + 32 * i + 1];
            }
            #pragma unroll
            for (int j = 0; j < 8; ++j)
                bb[j] = (double)Bs[cur][kk][tn + j];
            #pragma unroll
            for (int r = 0; r < 8; ++r)
                #pragma unroll
                for (int c = 0; c < 8; ++c)
                    acc[r][c] = fma(a[r], bb[c], acc[r][c]);
        }

        // write next tile into the other buffer (no hazard: other waves are
        // reading buf[cur], not buf[cur^1], until the barrier below)
        if (t < NT - 1) {
            const int nxt = cur ^ 1;
            As[nxt][sk + 0][sr] = na0.x; As[nxt][sk + 1][sr] = na0.y;
            As[nxt][sk + 2][sr] = na0.z; As[nxt][sk + 3][sr] = na0.w;
            As[nxt][sk + 4][sr] = na1.x; As[nxt][sk + 5][sr] = na1.y;
            As[nxt][sk + 6][sr] = na1.z; As[nxt][sk + 7][sr] = na1.w;
            Bs[nxt][sk + 0][sr] = nb0.x; Bs[nxt][sk + 1][sr] = nb0.y;
            Bs[nxt][sk + 2][sr] = nb0.z; Bs[nxt][sk + 3][sr] = nb0.w;
            Bs[nxt][sk + 4][sr] = nb1.x; Bs[nxt][sk + 5][sr] = nb1.y;
            Bs[nxt][sk + 6][sr] = nb1.z; Bs[nxt][sk + 7][sr] = nb1.w;
        }
        __syncthreads();
    }

    // epilogue: acc[r][c] -> MM[bm + 2*tm + 32*(r/2) + (r&1)][bn + tn + c]
    #pragma unroll
    for (int r = 0; r < 8; ++r) {
        const int row = bm + 2 * tm + 32 * (r >> 1) + (r & 1);
        double* mrow = MM + (size_t)row * D_DIM + bn + tn;
        #pragma unroll
        for (int c = 0; c < 8; ++c)
            mrow[c] = acc[r][c] + (double)bias[bn + tn + c];
    }
}

__global__ __launch_bounds__(256) void recur_kernel(
    const double* __restrict__ MM,
    float* __restrict__ out)   // fp32 outputs: m then s, each [T,B,D]
{
    const size_t stride = (size_t)B_DIM * D_DIM;  // 1,048,576
    const size_t idx = (size_t)blockIdx.x * 256 + threadIdx.x;  // b*D + o

    float* out_m = out;
    float* out_s = out + (size_t)T_DIM * stride;

    double m_prev = 0.0;
    double s_prev = 0.0;
    #pragma unroll
    for (int t = 0; t < T_DIM; ++t) {
        const double mm = MM[(size_t)t * stride + idx];
        const double m = mm + m_prev * (1.0 - s_prev) * 0.5;
        const double s = (m >= 1.0) ? 1.0 : 0.0;
        out_m[(size_t)t * stride + idx] = (float)m;
        out_s[(size_t)t * stride + idx] = (float)s;
        m_prev = m;
        s_prev = s;
    }
}

extern "C" void kernel_launch(void* const* d_in, const int* in_sizes, int n_in,
                              void* d_out, int out_size, void* d_ws, size_t ws_size,
                              hipStream_t stream) {
    // Identify inputs by element count (dict order is x, W, b).
    const float* x = (const float*)d_in[0];
    const float* W = (const float*)d_in[1];
    const float* b = (const float*)d_in[2];
    for (int i = 0; i < n_in; ++i) {
        if (in_sizes[i] == D_DIM) b = (const float*)d_in[i];
        else if (in_sizes[i] == D_DIM * D_DIM) W = (const float*)d_in[i];
        else if (in_sizes[i] == M_DIM * D_DIM) x = (const float*)d_in[i];
    }

    double* MM = (double*)d_ws;  // M_DIM*D_DIM*8 = 64 MiB

    dim3 grid_gemm(D_DIM / BN, M_DIM / BM);  // (32, 16) = 512 blocks
    gemm_f64v_kernel<<<grid_gemm, 256, 0, stream>>>(x, W, b, MM);

    const int n_bd = B_DIM * D_DIM;  // 1,048,576
    recur_kernel<<<n_bd / 256, 256, 0, stream>>>(MM, (float*)d_out);
}

// Round 6
// 1307.607 us; speedup vs baseline: 1.5580x; 1.1321x over previous
//
#include <hip/hip_runtime.h>
#include <hip/hip_bf16.h>

// Problem: x[T=8,B=256,D=4096] fp32; W[D,D] fp32 (row o, col i); b[D] fp32.
// mm[t,b,o] = sum_i x[t,b,i]*W[o,i] + b[o]
// m_t = mm_t + m_{t-1}*(1-s_{t-1})*0.5 ; s_t = (m_t >= 1.0)
// Outputs m,s each [T,B,D], fp32, concatenated in d_out.
//
// Precision: hard threshold -> fp64 accumulation mandatory (Round 3/5 verified).
// Round 6: f64 MFMA (v_mfma_f64_16x16x4f64). Round 4's failure was a C/D
// row-mapping ambiguity (blocked 4g+r vs strided g+4r). Fix: a 1-wave probe
// kernel asks the HW for its own C/D map via separable MFMAs
// (A[m][k]=m, B=delta(k==0) -> slot value = its row; transposed -> its col),
// stores the map in d_out (overwritten later by recur_kernel), and the GEMM
// epilogue indexes through the probed map. Works under ANY C/D convention.

#define T_DIM 8
#define B_DIM 256
#define D_DIM 4096
#define M_DIM (T_DIM * B_DIM)   // 2048 GEMM rows

#define BM 64
#define BN 64
#define BK 16
#define NT (D_DIM / BK)          // 256 K-tiles
#define LDSD (BM + 2)            // 66-double row stride

typedef double double4_t __attribute__((ext_vector_type(4)));

// ---- probe: learn the C/D lane->(row,col) map of v_mfma_f64_16x16x4f64 ----
__global__ __launch_bounds__(64) void mfma_probe_kernel(int* __restrict__ map)
{
    const int l = threadIdx.x;
    const int l16 = l & 15;
    const int g = l >> 4;           // k index under assumed A/B layout

    // A[m][k] = m (all k), B[n][k] = delta(k==0)  => D[m][n] = m
    const double am = (double)l16;
    const double bd = (g == 0) ? 1.0 : 0.0;
    // A[m][k] = delta(k==0), B[n][k] = n (all k)  => D[m][n] = n
    const double ad = (g == 0) ? 1.0 : 0.0;
    const double bn = (double)l16;

    double4_t z = {0.0, 0.0, 0.0, 0.0};
    double4_t dm = __builtin_amdgcn_mfma_f64_16x16x4f64(am, bd, z, 0, 0, 0);
    double4_t dn = __builtin_amdgcn_mfma_f64_16x16x4f64(ad, bn, z, 0, 0, 0);

    #pragma unroll
    for (int r = 0; r < 4; ++r) {
        map[l * 8 + r]     = ((int)dm[r]) & 15;  // row of slot (l, r)
        map[l * 8 + 4 + r] = ((int)dn[r]) & 15;  // col of slot (l, r)
    }
}

// ---- fp64 MFMA GEMM: 64x64 tile, 4 waves x (2x2 16x16 frags), BK=16 ----
__global__ __launch_bounds__(256) void gemm_f64_mfma_kernel(
    const float* __restrict__ X,    // [M_DIM][D_DIM]
    const float* __restrict__ W,    // [D_DIM][D_DIM] row-major [o][i]
    const float* __restrict__ bias, // [D_DIM]
    const int* __restrict__ map,    // probed C/D map (in d_out)
    double* __restrict__ MM)        // [M_DIM][D_DIM] fp64 scratch (64 MiB)
{
    __shared__ double As[2][BK][LDSD];   // [k][m], double-buffered
    __shared__ double Bs[2][BK][LDSD];

    const int tid = threadIdx.x;
    const int bm = blockIdx.y * BM;
    const int bn = blockIdx.x * BN;

    // staging: thread -> (row sr, k-quad sk); one float4 of X and of W per tile
    const int sr = tid >> 2;          // 0..63
    const int sk = (tid & 3) << 2;    // 0,4,8,12

    // 4 waves, each owns a 32x32 quadrant (2x2 MFMA 16x16 blocks)
    const int wave = tid >> 6;
    const int wr = (wave >> 1) << 5;  // 0 or 32
    const int wc = (wave & 1) << 5;   // 0 or 32
    const int lane = tid & 63;
    const int l16 = lane & 15;
    const int g = lane >> 4;

    double4_t acc00 = {0,0,0,0}, acc01 = {0,0,0,0};
    double4_t acc10 = {0,0,0,0}, acc11 = {0,0,0,0};

    const float* xp = X + (size_t)(bm + sr) * D_DIM + sk;
    const float* wp = W + (size_t)(bn + sr) * D_DIM + sk;

    // prologue: stage tile 0 into buffer 0
    {
        const float4 av = *reinterpret_cast<const float4*>(xp);
        const float4 bv = *reinterpret_cast<const float4*>(wp);
        As[0][sk + 0][sr] = (double)av.x; As[0][sk + 1][sr] = (double)av.y;
        As[0][sk + 2][sr] = (double)av.z; As[0][sk + 3][sr] = (double)av.w;
        Bs[0][sk + 0][sr] = (double)bv.x; Bs[0][sk + 1][sr] = (double)bv.y;
        Bs[0][sk + 2][sr] = (double)bv.z; Bs[0][sk + 3][sr] = (double)bv.w;
    }
    __syncthreads();

    for (int t = 0; t < NT; ++t) {
        const int cur = t & 1;

        // issue next-tile global loads early (hide HBM/L2 latency under MFMA)
        float4 av, bv;
        if (t < NT - 1) {
            const int k0 = (t + 1) * BK;
            av = *reinterpret_cast<const float4*>(xp + k0);
            bv = *reinterpret_cast<const float4*>(wp + k0);
        }

        // compute current tile: 16 MFMAs (4 per K=4 step)
        #pragma unroll
        for (int s = 0; s < 4; ++s) {
            const int kk = 4 * s + g;
            const double a0 = As[cur][kk][wr + l16];
            const double a1 = As[cur][kk][wr + 16 + l16];
            const double b0 = Bs[cur][kk][wc + l16];
            const double b1 = Bs[cur][kk][wc + 16 + l16];
            acc00 = __builtin_amdgcn_mfma_f64_16x16x4f64(a0, b0, acc00, 0, 0, 0);
            acc01 = __builtin_amdgcn_mfma_f64_16x16x4f64(a0, b1, acc01, 0, 0, 0);
            acc10 = __builtin_amdgcn_mfma_f64_16x16x4f64(a1, b0, acc10, 0, 0, 0);
            acc11 = __builtin_amdgcn_mfma_f64_16x16x4f64(a1, b1, acc11, 0, 0, 0);
        }

        // stage next tile into the other buffer
        if (t < NT - 1) {
            const int nxt = cur ^ 1;
            As[nxt][sk + 0][sr] = (double)av.x; As[nxt][sk + 1][sr] = (double)av.y;
            As[nxt][sk + 2][sr] = (double)av.z; As[nxt][sk + 3][sr] = (double)av.w;
            Bs[nxt][sk + 0][sr] = (double)bv.x; Bs[nxt][sk + 1][sr] = (double)bv.y;
            Bs[nxt][sk + 2][sr] = (double)bv.z; Bs[nxt][sk + 3][sr] = (double)bv.w;
        }
        __syncthreads();
    }

    // epilogue through the probed map: slot (lane, r) -> (row=mrow[r], col=mcol[r])
    int mrow[4], mcol[4];
    #pragma unroll
    for (int r = 0; r < 4; ++r) {
        mrow[r] = map[lane * 8 + r];
        mcol[r] = map[lane * 8 + 4 + r];
    }

    const double4_t* accs[4] = {&acc00, &acc01, &acc10, &acc11};
    #pragma unroll
    for (int mb = 0; mb < 2; ++mb) {
        #pragma unroll
        for (int nb = 0; nb < 2; ++nb) {
            const double4_t a = *accs[mb * 2 + nb];
            #pragma unroll
            for (int r = 0; r < 4; ++r) {
                const int row = bm + wr + mb * 16 + mrow[r];
                const int col = bn + wc + nb * 16 + mcol[r];
                MM[(size_t)row * D_DIM + col] = a[r] + (double)bias[col];
            }
        }
    }
}

__global__ __launch_bounds__(256) void recur_kernel(
    const double* __restrict__ MM,
    float* __restrict__ out)   // fp32 outputs: m then s, each [T,B,D]
{
    const size_t stride = (size_t)B_DIM * D_DIM;  // 1,048,576
    const size_t idx = (size_t)blockIdx.x * 256 + threadIdx.x;

    float* out_m = out;
    float* out_s = out + (size_t)T_DIM * stride;

    double m_prev = 0.0;
    double s_prev = 0.0;
    #pragma unroll
    for (int t = 0; t < T_DIM; ++t) {
        const double mm = MM[(size_t)t * stride + idx];
        const double m = mm + m_prev * (1.0 - s_prev) * 0.5;
        const double s = (m >= 1.0) ? 1.0 : 0.0;
        out_m[(size_t)t * stride + idx] = (float)m;
        out_s[(size_t)t * stride + idx] = (float)s;
        m_prev = m;
        s_prev = s;
    }
}

extern "C" void kernel_launch(void* const* d_in, const int* in_sizes, int n_in,
                              void* d_out, int out_size, void* d_ws, size_t ws_size,
                              hipStream_t stream) {
    // Identify inputs by element count (dict order is x, W, b).
    const float* x = (const float*)d_in[0];
    const float* W = (const float*)d_in[1];
    const float* b = (const float*)d_in[2];
    for (int i = 0; i < n_in; ++i) {
        if (in_sizes[i] == D_DIM) b = (const float*)d_in[i];
        else if (in_sizes[i] == D_DIM * D_DIM) W = (const float*)d_in[i];
        else if (in_sizes[i] == M_DIM * D_DIM) x = (const float*)d_in[i];
    }

    double* MM = (double*)d_ws;        // M_DIM*D_DIM*8 = 64 MiB
    int* map = (int*)d_out;            // 512 ints; recur_kernel overwrites all
                                       // of d_out afterwards (stream-ordered)

    mfma_probe_kernel<<<1, 64, 0, stream>>>(map);

    dim3 grid_gemm(D_DIM / BN, M_DIM / BM);  // (64, 32) = 2048 blocks
    gemm_f64_mfma_kernel<<<grid_gemm, 256, 0, stream>>>(x, W, b, map, MM);

    const int n_bd = B_DIM * D_DIM;  // 1,048,576
    recur_kernel<<<n_bd / 256, 256, 0, stream>>>(MM, (float*)d_out);
}

// Round 10
// 1188.451 us; speedup vs baseline: 1.7142x; 1.1003x over previous
//
#include <hip/hip_runtime.h>
#include <hip/hip_bf16.h>

// Problem: x[T=8,B=256,D=4096] fp32; W[D,D] fp32 (row o, col i); b[D] fp32.
// mm[t,b,o] = sum_i x[t,b,i]*W[o,i] + b[o]
// m_t = mm_t + m_{t-1}*(1-s_{t-1})*0.5 ; s_t = (m_t >= 1.0)
// Outputs m,s each [T,B,D], fp32, concatenated in d_out.
//
// Precision: hard threshold -> fp64 accumulation mandatory (R3/R5/R6 verified).
// R6 verified the f64-MFMA path via the HW-probed C/D map (1337us, MfmaUtil 72%,
// occupancy 42% -- LDS-capped at 4 blocks/CU).
// R7: float-in-LDS (convert at frag read, bit-identical), LDS 33.8->18.4KB ->
// 8 blocks/CU; row stride 72 floats (=8 mod 32 banks) so quarter-wave frag
// reads are max 2-way per bank (free).

#define T_DIM 8
#define B_DIM 256
#define D_DIM 4096
#define M_DIM (T_DIM * B_DIM)   // 2048 GEMM rows

#define BM 64
#define BN 64
#define BK 16
#define NT (D_DIM / BK)          // 256 K-tiles
#define LDSF 72                  // float row stride: 72 mod 32 banks = 8

typedef double double4_t __attribute__((ext_vector_type(4)));

// ---- probe: learn the C/D lane->(row,col) map of v_mfma_f64_16x16x4f64 ----
__global__ __launch_bounds__(64) void mfma_probe_kernel(int* __restrict__ map)
{
    const int l = threadIdx.x;
    const int l16 = l & 15;
    const int g = l >> 4;           // k index under assumed A/B layout

    // A[m][k] = m (all k), B[n][k] = delta(k==0)  => D[m][n] = m
    const double am = (double)l16;
    const double bd = (g == 0) ? 1.0 : 0.0;
    // A[m][k] = delta(k==0), B[n][k] = n (all k)  => D[m][n] = n
    const double ad = (g == 0) ? 1.0 : 0.0;
    const double bn = (double)l16;

    double4_t z = {0.0, 0.0, 0.0, 0.0};
    double4_t dm = __builtin_amdgcn_mfma_f64_16x16x4f64(am, bd, z, 0, 0, 0);
    double4_t dn = __builtin_amdgcn_mfma_f64_16x16x4f64(ad, bn, z, 0, 0, 0);

    #pragma unroll
    for (int r = 0; r < 4; ++r) {
        map[l * 8 + r]     = ((int)dm[r]) & 15;  // row of slot (l, r)
        map[l * 8 + 4 + r] = ((int)dn[r]) & 15;  // col of slot (l, r)
    }
}

// ---- fp64 MFMA GEMM: 64x64 tile, 4 waves x (2x2 16x16 frags), BK=16 ----
__global__ __launch_bounds__(256, 8) void gemm_f64_mfma_kernel(
    const float* __restrict__ X,    // [M_DIM][D_DIM]
    const float* __restrict__ W,    // [D_DIM][D_DIM] row-major [o][i]
    const float* __restrict__ bias, // [D_DIM]
    const int* __restrict__ map,    // probed C/D map (in d_out)
    double* __restrict__ MM)        // [M_DIM][D_DIM] fp64 scratch (64 MiB)
{
    // float tiles, [k][m] layout, double-buffered; convert to f64 at read
    __shared__ float As[2][BK][LDSF];
    __shared__ float Bs[2][BK][LDSF];

    const int tid = threadIdx.x;
    const int bm = blockIdx.y * BM;
    const int bn = blockIdx.x * BN;

    // staging: thread -> (row sr, k-quad sk); one float4 of X and of W per tile
    const int sr = tid >> 2;          // 0..63
    const int sk = (tid & 3) << 2;    // 0,4,8,12

    // 4 waves, each owns a 32x32 quadrant (2x2 MFMA 16x16 blocks)
    const int wave = tid >> 6;
    const int wr = (wave >> 1) << 5;  // 0 or 32
    const int wc = (wave & 1) << 5;   // 0 or 32
    const int lane = tid & 63;
    const int l16 = lane & 15;
    const int g = lane >> 4;

    double4_t acc00 = {0,0,0,0}, acc01 = {0,0,0,0};
    double4_t acc10 = {0,0,0,0}, acc11 = {0,0,0,0};

    const float* xp = X + (size_t)(bm + sr) * D_DIM + sk;
    const float* wp = W + (size_t)(bn + sr) * D_DIM + sk;

    // prologue: stage tile 0 into buffer 0
    {
        const float4 av = *reinterpret_cast<const float4*>(xp);
        const float4 bv = *reinterpret_cast<const float4*>(wp);
        As[0][sk + 0][sr] = av.x; As[0][sk + 1][sr] = av.y;
        As[0][sk + 2][sr] = av.z; As[0][sk + 3][sr] = av.w;
        Bs[0][sk + 0][sr] = bv.x; Bs[0][sk + 1][sr] = bv.y;
        Bs[0][sk + 2][sr] = bv.z; Bs[0][sk + 3][sr] = bv.w;
    }
    __syncthreads();

    for (int t = 0; t < NT; ++t) {
        const int cur = t & 1;

        // issue next-tile global loads early (hide HBM/L2 latency under MFMA)
        float4 av, bv;
        if (t < NT - 1) {
            const int k0 = (t + 1) * BK;
            av = *reinterpret_cast<const float4*>(xp + k0);
            bv = *reinterpret_cast<const float4*>(wp + k0);
        }

        // compute current tile: 16 MFMAs (4 per K=4 step)
        #pragma unroll
        for (int s = 0; s < 4; ++s) {
            const int kk = 4 * s + g;
            const double a0 = (double)As[cur][kk][wr + l16];
            const double a1 = (double)As[cur][kk][wr + 16 + l16];
            const double b0 = (double)Bs[cur][kk][wc + l16];
            const double b1 = (double)Bs[cur][kk][wc + 16 + l16];
            acc00 = __builtin_amdgcn_mfma_f64_16x16x4f64(a0, b0, acc00, 0, 0, 0);
            acc01 = __builtin_amdgcn_mfma_f64_16x16x4f64(a0, b1, acc01, 0, 0, 0);
            acc10 = __builtin_amdgcn_mfma_f64_16x16x4f64(a1, b0, acc10, 0, 0, 0);
            acc11 = __builtin_amdgcn_mfma_f64_16x16x4f64(a1, b1, acc11, 0, 0, 0);
        }

        // stage next tile into the other buffer
        if (t < NT - 1) {
            const int nxt = cur ^ 1;
            As[nxt][sk + 0][sr] = av.x; As[nxt][sk + 1][sr] = av.y;
            As[nxt][sk + 2][sr] = av.z; As[nxt][sk + 3][sr] = av.w;
            Bs[nxt][sk + 0][sr] = bv.x; Bs[nxt][sk + 1][sr] = bv.y;
            Bs[nxt][sk + 2][sr] = bv.z; Bs[nxt][sk + 3][sr] = bv.w;
        }
        __syncthreads();
    }

    // epilogue through the probed map: slot (lane, r) -> (row, col)
    int mrow[4], mcol[4];
    #pragma unroll
    for (int r = 0; r < 4; ++r) {
        mrow[r] = map[lane * 8 + r];
        mcol[r] = map[lane * 8 + 4 + r];
    }

    const double4_t* accs[4] = {&acc00, &acc01, &acc10, &acc11};
    #pragma unroll
    for (int mb = 0; mb < 2; ++mb) {
        #pragma unroll
        for (int nb = 0; nb < 2; ++nb) {
            const double4_t a = *accs[mb * 2 + nb];
            #pragma unroll
            for (int r = 0; r < 4; ++r) {
                const int row = bm + wr + mb * 16 + mrow[r];
                const int col = bn + wc + nb * 16 + mcol[r];
                MM[(size_t)row * D_DIM + col] = a[r] + (double)bias[col];
            }
        }
    }
}

__global__ __launch_bounds__(256) void recur_kernel(
    const double* __restrict__ MM,
    float* __restrict__ out)   // fp32 outputs: m then s, each [T,B,D]
{
    const size_t stride = (size_t)B_DIM * D_DIM;  // 1,048,576
    const size_t idx = (size_t)blockIdx.x * 256 + threadIdx.x;

    float* out_m = out;
    float* out_s = out + (size_t)T_DIM * stride;

    double m_prev = 0.0;
    double s_prev = 0.0;
    #pragma unroll
    for (int t = 0; t < T_DIM; ++t) {
        const double mm = MM[(size_t)t * stride + idx];
        const double m = mm + m_prev * (1.0 - s_prev) * 0.5;
        const double s = (m >= 1.0) ? 1.0 : 0.0;
        out_m[(size_t)t * stride + idx] = (float)m;
        out_s[(size_t)t * stride + idx] = (float)s;
        m_prev = m;
        s_prev = s;
    }
}

extern "C" void kernel_launch(void* const* d_in, const int* in_sizes, int n_in,
                              void* d_out, int out_size, void* d_ws, size_t ws_size,
                              hipStream_t stream) {
    // Identify inputs by element count (dict order is x, W, b).
    const float* x = (const float*)d_in[0];
    const float* W = (const float*)d_in[1];
    const float* b = (const float*)d_in[2];
    for (int i = 0; i < n_in; ++i) {
        if (in_sizes[i] == D_DIM) b = (const float*)d_in[i];
        else if (in_sizes[i] == D_DIM * D_DIM) W = (const float*)d_in[i];
        else if (in_sizes[i] == M_DIM * D_DIM) x = (const float*)d_in[i];
    }

    double* MM = (double*)d_ws;        // M_DIM*D_DIM*8 = 64 MiB
    int* map = (int*)d_out;            // 512 ints; recur_kernel overwrites all
                                       // of d_out afterwards (stream-ordered)

    mfma_probe_kernel<<<1, 64, 0, stream>>>(map);

    dim3 grid_gemm(D_DIM / BN, M_DIM / BM);  // (64, 32) = 2048 blocks
    gemm_f64_mfma_kernel<<<grid_gemm, 256, 0, stream>>>(x, W, b, map, MM);

    const int n_bd = B_DIM * D_DIM;  // 1,048,576
    recur_kernel<<<n_bd / 256, 256, 0, stream>>>(MM, (float*)d_out);
}